// Round 6
// baseline (639.287 us; speedup 1.0000x reference)
//
#include <hip/hip_runtime.h>
#include <hip/hip_bf16.h>
#include <hip/hip_cooperative_groups.h>

namespace cg = cooperative_groups;

#define N_NODES 40000
#define N_EDGES 640000
#define DIM 128
#define N_OPS 5
#define EPS 1e-5f

#define NC 640                       // csr_build blocks
#define CH 63                        // nodes per chunk (640*63 = 40320 >= 40000)
#define GATHER_NB 2048               // gather grid
#define PART_W (2 * N_OPS * DIM)     // 1280 floats per partial block

// ---- K1 (cooperative): zero + hist + scan + csr fill, all in one ----
__global__ void __launch_bounds__(256)
csr_build_kernel(const int* __restrict__ ei,
                 int* __restrict__ cnt, int* __restrict__ bsum,
                 int* __restrict__ offs, int* __restrict__ cursor,
                 int* __restrict__ csr_src) {
  cg::grid_group grid = cg::this_grid();
  const int tid  = threadIdx.x;
  const int bid  = blockIdx.x;
  const int gtid = bid * 256 + tid;
  const int gsz  = NC * 256;                 // 163840

  // P0: zero counters
  for (int i = gtid; i < N_NODES; i += gsz) cnt[i] = 0;
  if (gtid == 0) offs[N_NODES] = N_EDGES;
  grid.sync();

  // P1: histogram of dst
  for (int e = gtid; e < N_EDGES; e += gsz) atomicAdd(&cnt[ei[N_EDGES + e]], 1);
  grid.sync();

  // P2: chunk totals (wave 0 of each block, CH<=63 elems)
  if (tid < 64) {
    const int i = bid * CH + tid;
    int x = (tid < CH && i < N_NODES) ? cnt[i] : 0;
    int v = x;
#pragma unroll
    for (int off = 1; off < 64; off <<= 1) {
      int t = __shfl_up(v, off, 64);
      if (tid >= off) v += t;
    }
    if (tid == 63) bsum[bid] = v;            // lane63 x=0 -> v = chunk total
  }
  grid.sync();

  // P3: chunk base + local exclusive scan -> offs/cursor
  __shared__ int sb[NC];
  __shared__ int sbase;
  for (int k = tid; k < NC; k += 256) sb[k] = bsum[k];
  __syncthreads();
  if (tid == 0) {
    int a = 0;
    for (int k = 0; k < bid; ++k) a += sb[k];
    sbase = a;
  }
  __syncthreads();
  if (tid < 64) {
    const int i = bid * CH + tid;
    int x = (tid < CH && i < N_NODES) ? cnt[i] : 0;
    int v = x;
#pragma unroll
    for (int off = 1; off < 64; off <<= 1) {
      int t = __shfl_up(v, off, 64);
      if (tid >= off) v += t;
    }
    const int excl = v - x + sbase;
    if (tid < CH && i < N_NODES) { offs[i] = excl; cursor[i] = excl; }
  }
  grid.sync();

  // P4: fill CSR (src grouped by dst)
  for (int e = gtid; e < N_EDGES; e += gsz) {
    const int pos = atomicAdd(&cursor[ei[N_EDGES + e]], 1);
    csr_src[pos] = ei[e];
  }
}

// ---- K2: wave-per-node gather (R2 inner loop) + fused all-branch stats ----
__global__ void __launch_bounds__(256, 8)
gather_stats_kernel(const int* __restrict__ csr_src,
                    const int* __restrict__ offs,
                    const float* __restrict__ h,
                    const float* __restrict__ h_in,
                    float* __restrict__ agg_sum,
                    float* __restrict__ agg_max,
                    float* __restrict__ deg,
                    float* __restrict__ partials) {
  __shared__ float lsum[N_OPS * DIM], lssq[N_OPS * DIM];
  for (int i = threadIdx.x; i < N_OPS * DIM; i += blockDim.x) { lsum[i] = 0.f; lssq[i] = 0.f; }
  __syncthreads();

  const int lane  = threadIdx.x & 63;
  const int wave  = (int)((blockIdx.x * blockDim.x + threadIdx.x) >> 6);
  const int nwave = (int)((gridDim.x * blockDim.x) >> 6);

  float s0x = 0, q0x = 0, s0y = 0, q0y = 0;
  float s1x = 0, q1x = 0, s1y = 0, q1y = 0;
  float s2x = 0, q2x = 0, s2y = 0, q2y = 0;
  float s3x = 0, q3x = 0, s3y = 0, q3y = 0;
  float s4x = 0, q4x = 0, s4y = 0, q4y = 0;

  for (int n = wave; n < N_NODES; n += nwave) {
    const int beg = offs[n], end = offs[n + 1];
    float sx = 0.f, sy = 0.f;
    float mx = -INFINITY, my = -INFINITY;
    int e = beg;
    for (; e + 3 < end; e += 4) {
      const int i0 = csr_src[e], i1 = csr_src[e + 1];
      const int i2 = csr_src[e + 2], i3 = csr_src[e + 3];
      const float2 a = *reinterpret_cast<const float2*>(h + (size_t)i0 * DIM + lane * 2);
      const float2 b = *reinterpret_cast<const float2*>(h + (size_t)i1 * DIM + lane * 2);
      const float2 c = *reinterpret_cast<const float2*>(h + (size_t)i2 * DIM + lane * 2);
      const float2 d = *reinterpret_cast<const float2*>(h + (size_t)i3 * DIM + lane * 2);
      sx += a.x + b.x + c.x + d.x;
      sy += a.y + b.y + c.y + d.y;
      mx = fmaxf(fmaxf(fmaxf(mx, a.x), fmaxf(b.x, c.x)), d.x);
      my = fmaxf(fmaxf(fmaxf(my, a.y), fmaxf(b.y, c.y)), d.y);
    }
    for (; e < end; ++e) {
      const int i0 = csr_src[e];
      const float2 a = *reinterpret_cast<const float2*>(h + (size_t)i0 * DIM + lane * 2);
      sx += a.x; sy += a.y;
      mx = fmaxf(mx, a.x); my = fmaxf(my, a.y);
    }
    const int dg = end - beg;
    if (dg == 0) { mx = 0.f; my = 0.f; }  // empty segment -> 0 (isfinite mask)
    *reinterpret_cast<float2*>(agg_sum + (size_t)n * DIM + lane * 2) = make_float2(sx, sy);
    *reinterpret_cast<float2*>(agg_max + (size_t)n * DIM + lane * 2) = make_float2(mx, my);
    if (lane == 0) deg[n] = (float)dg;

    // fused stats (branches 0..4), this node's columns 2*lane, 2*lane+1
    const float2 hv  = *reinterpret_cast<const float2*>(h + (size_t)n * DIM + lane * 2);
    const float2 hiv = *reinterpret_cast<const float2*>(h_in + (size_t)n * DIM + lane * 2);
    const float inv = 1.0f / fmaxf((float)dg, 1.0f);
    const float mnx = sx * inv, mny = sy * inv;
    s0x += hv.x;  q0x += hv.x * hv.x;   s0y += hv.y;  q0y += hv.y * hv.y;
    s1x += hiv.x; q1x += hiv.x * hiv.x; s1y += hiv.y; q1y += hiv.y * hiv.y;
    s2x += sx;    q2x += sx * sx;       s2y += sy;    q2y += sy * sy;
    s3x += mnx;   q3x += mnx * mnx;     s3y += mny;   q3y += mny * mny;
    s4x += mx;    q4x += mx * mx;       s4y += my;    q4y += my * my;
  }

  const int cA = 2 * lane, cB = 2 * lane + 1;
  atomicAdd(&lsum[0 * DIM + cA], s0x); atomicAdd(&lssq[0 * DIM + cA], q0x);
  atomicAdd(&lsum[0 * DIM + cB], s0y); atomicAdd(&lssq[0 * DIM + cB], q0y);
  atomicAdd(&lsum[1 * DIM + cA], s1x); atomicAdd(&lssq[1 * DIM + cA], q1x);
  atomicAdd(&lsum[1 * DIM + cB], s1y); atomicAdd(&lssq[1 * DIM + cB], q1y);
  atomicAdd(&lsum[2 * DIM + cA], s2x); atomicAdd(&lssq[2 * DIM + cA], q2x);
  atomicAdd(&lsum[2 * DIM + cB], s2y); atomicAdd(&lssq[2 * DIM + cB], q2y);
  atomicAdd(&lsum[3 * DIM + cA], s3x); atomicAdd(&lssq[3 * DIM + cA], q3x);
  atomicAdd(&lsum[3 * DIM + cB], s3y); atomicAdd(&lssq[3 * DIM + cB], q3y);
  atomicAdd(&lsum[4 * DIM + cA], s4x); atomicAdd(&lssq[4 * DIM + cA], q4x);
  atomicAdd(&lsum[4 * DIM + cB], s4y); atomicAdd(&lssq[4 * DIM + cB], q4y);
  __syncthreads();

  float* p = partials + (size_t)blockIdx.x * PART_W;
  for (int i = threadIdx.x; i < N_OPS * DIM; i += blockDim.x) {
    p[i] = lsum[i];
    p[N_OPS * DIM + i] = lssq[i];
  }
}

// ---- K3: fold 2048 partials -> mu / rsig ----
__global__ void reduce_stats(const float* __restrict__ partials,
                             float* __restrict__ mu, float* __restrict__ rsig) {
  const int i = blockIdx.x * blockDim.x + threadIdx.x;   // 768 threads, use 640
  if (i >= N_OPS * DIM) return;
  float ss = 0.f, sq = 0.f;
#pragma unroll 4
  for (int b = 0; b < GATHER_NB; ++b) {
    const float* p = partials + (size_t)b * PART_W;
    ss += p[i];
    sq += p[N_OPS * DIM + i];
  }
  const float invn = 1.0f / (float)N_NODES;
  const float m = ss * invn;
  float v = sq * invn - m * m;
  v = fmaxf(v, 0.0f);
  mu[i]   = m;
  rsig[i] = rsqrtf(v + EPS);
}

// ---- K4: fused BN + ReLU + weighted sum, float4 (agg_max aliases d_out) ----
__global__ void out_kernel(const float* __restrict__ h,
                           const float* __restrict__ h_in,
                           const float* __restrict__ agg_sum,
                           const float* __restrict__ agg_max,
                           const float* __restrict__ deg,
                           const float* __restrict__ mu,
                           const float* __restrict__ rsig,
                           const float* __restrict__ gamma,
                           const float* __restrict__ beta,
                           const float* __restrict__ w,
                           float* __restrict__ out) {
  __shared__ float smu[N_OPS * DIM], srs[N_OPS * DIM], sg[N_OPS * DIM], sb[N_OPS * DIM];
  __shared__ float sw[N_OPS];
  for (int i = threadIdx.x; i < N_OPS * DIM; i += blockDim.x) {
    smu[i] = mu[i]; srs[i] = rsig[i]; sg[i] = gamma[i]; sb[i] = beta[i];
  }
  if (threadIdx.x < N_OPS) sw[threadIdx.x] = w[threadIdx.x];
  __syncthreads();

  const int ngroups = N_NODES * (DIM / 4);
  for (int g = blockIdx.x * blockDim.x + threadIdx.x; g < ngroups;
       g += gridDim.x * blockDim.x) {
    const int n  = g >> 5;
    const int d4 = (g & 31) * 4;
    const size_t off = (size_t)n * DIM + d4;

    const float4 v0 = *reinterpret_cast<const float4*>(h + off);
    const float4 v1 = *reinterpret_cast<const float4*>(h_in + off);
    const float4 v2 = *reinterpret_cast<const float4*>(agg_sum + off);
    const float4 v4 = *reinterpret_cast<const float4*>(agg_max + off);
    const float dg  = deg[n];
    const float inv = 1.0f / fmaxf(dg, 1.0f);

    float vals[N_OPS][4];
    vals[0][0] = v0.x; vals[0][1] = v0.y; vals[0][2] = v0.z; vals[0][3] = v0.w;
    vals[1][0] = v1.x; vals[1][1] = v1.y; vals[1][2] = v1.z; vals[1][3] = v1.w;
    vals[2][0] = v2.x; vals[2][1] = v2.y; vals[2][2] = v2.z; vals[2][3] = v2.w;
    vals[3][0] = v2.x * inv; vals[3][1] = v2.y * inv;
    vals[3][2] = v2.z * inv; vals[3][3] = v2.w * inv;
    vals[4][0] = v4.x; vals[4][1] = v4.y; vals[4][2] = v4.z; vals[4][3] = v4.w;

    float acc[4] = {0.0f, 0.0f, 0.0f, 0.0f};
#pragma unroll
    for (int b = 0; b < N_OPS; ++b) {
      const float wb = sw[b];
#pragma unroll
      for (int c = 0; c < 4; ++c) {
        const int dd = b * DIM + d4 + c;
        const float xh = (vals[b][c] - smu[dd]) * srs[dd];
        const float y  = fmaf(sg[dd], xh, sb[dd]);
        acc[c] = fmaf(wb, fmaxf(y, 0.0f), acc[c]);
      }
    }
    *reinterpret_cast<float4*>(out + off) = make_float4(acc[0], acc[1], acc[2], acc[3]);
  }
}

extern "C" void kernel_launch(void* const* d_in, const int* in_sizes, int n_in,
                              void* d_out, int out_size, void* d_ws, size_t ws_size,
                              hipStream_t stream) {
  const int*   ei    = (const int*)d_in[1];
  const float* h     = (const float*)d_in[2];
  const float* h_in  = (const float*)d_in[3];
  const float* gamma = (const float*)d_in[4];
  const float* beta  = (const float*)d_in[5];
  const float* w     = (const float*)d_in[0];
  float* out = (float*)d_out;

  const size_t ND = (size_t)N_NODES * DIM;
  float* ws       = (float*)d_ws;
  float* agg_sum  = ws;                                    // ND floats
  int*   cnt      = (int*)(ws + ND);                       // N
  int*   offs     = cnt + N_NODES;                         // N+1
  int*   cursor   = offs + N_NODES + 1;                    // N
  float* deg      = (float*)(cursor + N_NODES);            // N
  int*   csr_src  = (int*)(deg + N_NODES);                 // E
  int*   bsum     = csr_src + N_EDGES;                     // NC
  float* partials = (float*)(bsum + ((NC + 3) & ~3));      // 2048*1280 floats
  float* mu       = partials + (size_t)GATHER_NB * PART_W; // 640
  float* rsig     = mu + N_OPS * DIM;                      // 640
  float* agg_max  = out;                                   // ND floats (overwritten last)

  {
    void* args[] = { (void*)&ei, (void*)&cnt, (void*)&bsum,
                     (void*)&offs, (void*)&cursor, (void*)&csr_src };
    hipLaunchCooperativeKernel((const void*)csr_build_kernel,
                               dim3(NC), dim3(256), args, 0, stream);
  }
  gather_stats_kernel<<<GATHER_NB, 256, 0, stream>>>(csr_src, offs, h, h_in,
                                                     agg_sum, agg_max, deg, partials);
  reduce_stats<<<3, 256, 0, stream>>>(partials, mu, rsig);
  out_kernel<<<2048, 256, 0, stream>>>(h, h_in, agg_sum, agg_max, deg, mu, rsig,
                                       gamma, beta, w, out);
}

// Round 7
// 191.379 us; speedup vs baseline: 3.3404x; 3.3404x over previous
//
#include <hip/hip_runtime.h>
#include <hip/hip_bf16.h>

#define N_NODES 40000
#define N_EDGES 640000
#define DIM 128
#define N_OPS 5
#define EPS 1e-5f
#define SCAN_CHUNK 4096
#define SCAN_NB ((N_NODES + SCAN_CHUNK - 1) / SCAN_CHUNK)   // 10
#define GATHER_NB 2048
#define PART_W (2 * N_OPS * DIM)     // 1280 floats per partial row [sum|ssq]
#define RED_NB 64                    // partial-fold blocks (64*32 = 2048)

// ---- K1: histogram of dst (4 edges/thread, int4) ----
__global__ void hist_kernel(const int* __restrict__ ei, int* __restrict__ cnt) {
  const int t = blockIdx.x * blockDim.x + threadIdx.x;
  if (t < N_EDGES / 4) {
    const int4 d = reinterpret_cast<const int4*>(ei + N_EDGES)[t];
    atomicAdd(&cnt[d.x], 1);
    atomicAdd(&cnt[d.y], 1);
    atomicAdd(&cnt[d.z], 1);
    atomicAdd(&cnt[d.w], 1);
  }
}

// ---- K2a: per-chunk totals (10 blocks x 1024) ----
__global__ void scanA_kernel(const int* __restrict__ cnt, int* __restrict__ bsum) {
  __shared__ int ws[16];
  const int tid = threadIdx.x, b = blockIdx.x;
  const int i0 = b * SCAN_CHUNK + tid * 4;
  int s = 0;
  if (i0 + 3 < N_NODES) {
    const int4 x = *reinterpret_cast<const int4*>(cnt + i0);
    s = x.x + x.y + x.z + x.w;
  } else {
#pragma unroll
    for (int k = 0; k < 4; ++k) if (i0 + k < N_NODES) s += cnt[i0 + k];
  }
#pragma unroll
  for (int off = 32; off; off >>= 1) s += __shfl_down(s, off, 64);
  if ((tid & 63) == 0) ws[tid >> 6] = s;
  __syncthreads();
  if (tid == 0) {
    int t = 0;
#pragma unroll
    for (int k = 0; k < 16; ++k) t += ws[k];
    bsum[b] = t;
  }
}

// ---- K2b: local exclusive scan per chunk; chunk base derived inline ----
__global__ void scanC_kernel(const int* __restrict__ cnt, const int* __restrict__ bsum,
                             int* __restrict__ offs, int* __restrict__ cursor) {
  __shared__ int wsum[16];
  __shared__ int sbase;
  const int tid  = threadIdx.x;       // 1024
  const int lane = tid & 63;
  const int wid  = tid >> 6;
  const int b    = blockIdx.x;
  if (tid == 0) {
    int acc = 0;
    for (int k = 0; k < b; ++k) acc += bsum[k];
    sbase = acc;
  }
  const int i0 = b * SCAN_CHUNK + tid * 4;
  int x0 = 0, x1 = 0, x2 = 0, x3 = 0;
  if (i0 + 3 < N_NODES) {
    const int4 x4 = *reinterpret_cast<const int4*>(cnt + i0);
    x0 = x4.x; x1 = x4.y; x2 = x4.z; x3 = x4.w;
  } else if (i0 < N_NODES) {
    x0 = cnt[i0];
    if (i0 + 1 < N_NODES) x1 = cnt[i0 + 1];
    if (i0 + 2 < N_NODES) x2 = cnt[i0 + 2];
  }
  const int my4 = x0 + x1 + x2 + x3;
  int v = my4;
#pragma unroll
  for (int off = 1; off < 64; off <<= 1) {
    int t = __shfl_up(v, off, 64);
    if (lane >= off) v += t;
  }
  if (lane == 63) wsum[wid] = v;
  __syncthreads();
  if (wid == 0 && lane < 16) {
    int wv = wsum[lane];
#pragma unroll
    for (int off = 1; off < 16; off <<= 1) {
      int t = __shfl_up(wv, off, 64);
      if (lane >= off) wv += t;
    }
    wsum[lane] = wv;
  }
  __syncthreads();
  const int wave_excl = (wid == 0) ? 0 : wsum[wid - 1];
  int excl = v - my4 + wave_excl + sbase;
  if (i0 < N_NODES) {
    offs[i0] = excl; cursor[i0] = excl; excl += x0;
    if (i0 + 1 < N_NODES) { offs[i0 + 1] = excl; cursor[i0 + 1] = excl; excl += x1; }
    if (i0 + 2 < N_NODES) { offs[i0 + 2] = excl; cursor[i0 + 2] = excl; excl += x2; }
    if (i0 + 3 < N_NODES) { offs[i0 + 3] = excl; cursor[i0 + 3] = excl; }
  }
  if (b == 0 && tid == 0) offs[N_NODES] = N_EDGES;
}

// ---- K3: fill CSR (4 edges/thread, int4) ----
__global__ void csr_fill_kernel(const int* __restrict__ ei, int* __restrict__ cursor,
                                int* __restrict__ csr_src) {
  const int t = blockIdx.x * blockDim.x + threadIdx.x;
  if (t < N_EDGES / 4) {
    const int4 s = reinterpret_cast<const int4*>(ei)[t];
    const int4 d = reinterpret_cast<const int4*>(ei + N_EDGES)[t];
    csr_src[atomicAdd(&cursor[d.x], 1)] = s.x;
    csr_src[atomicAdd(&cursor[d.y], 1)] = s.y;
    csr_src[atomicAdd(&cursor[d.z], 1)] = s.z;
    csr_src[atomicAdd(&cursor[d.w], 1)] = s.w;
  }
}

// ---- K4: wave-per-node gather (R2 inner loop) + fused all-branch stats ----
__global__ void __launch_bounds__(256)
gather_stats_kernel(const int* __restrict__ csr_src,
                    const int* __restrict__ offs,
                    const float* __restrict__ h,
                    const float* __restrict__ h_in,
                    float* __restrict__ agg_sum,
                    float* __restrict__ agg_max,
                    float* __restrict__ deg,
                    float* __restrict__ partials) {
  __shared__ float lsum[N_OPS * DIM], lssq[N_OPS * DIM];
  for (int i = threadIdx.x; i < N_OPS * DIM; i += blockDim.x) { lsum[i] = 0.f; lssq[i] = 0.f; }
  __syncthreads();

  const int lane  = threadIdx.x & 63;
  const int wave  = (int)((blockIdx.x * blockDim.x + threadIdx.x) >> 6);
  const int nwave = (int)((gridDim.x * blockDim.x) >> 6);

  float s0x = 0, q0x = 0, s0y = 0, q0y = 0;
  float s1x = 0, q1x = 0, s1y = 0, q1y = 0;
  float s2x = 0, q2x = 0, s2y = 0, q2y = 0;
  float s3x = 0, q3x = 0, s3y = 0, q3y = 0;
  float s4x = 0, q4x = 0, s4y = 0, q4y = 0;

  for (int n = wave; n < N_NODES; n += nwave) {
    const int beg = offs[n], end = offs[n + 1];
    float sx = 0.f, sy = 0.f;
    float mx = -INFINITY, my = -INFINITY;
    int e = beg;
    for (; e + 3 < end; e += 4) {
      const int i0 = csr_src[e], i1 = csr_src[e + 1];
      const int i2 = csr_src[e + 2], i3 = csr_src[e + 3];
      const float2 a = *reinterpret_cast<const float2*>(h + (size_t)i0 * DIM + lane * 2);
      const float2 b = *reinterpret_cast<const float2*>(h + (size_t)i1 * DIM + lane * 2);
      const float2 c = *reinterpret_cast<const float2*>(h + (size_t)i2 * DIM + lane * 2);
      const float2 d = *reinterpret_cast<const float2*>(h + (size_t)i3 * DIM + lane * 2);
      sx += a.x + b.x + c.x + d.x;
      sy += a.y + b.y + c.y + d.y;
      mx = fmaxf(fmaxf(fmaxf(mx, a.x), fmaxf(b.x, c.x)), d.x);
      my = fmaxf(fmaxf(fmaxf(my, a.y), fmaxf(b.y, c.y)), d.y);
    }
    for (; e < end; ++e) {
      const int i0 = csr_src[e];
      const float2 a = *reinterpret_cast<const float2*>(h + (size_t)i0 * DIM + lane * 2);
      sx += a.x; sy += a.y;
      mx = fmaxf(mx, a.x); my = fmaxf(my, a.y);
    }
    const int dg = end - beg;
    if (dg == 0) { mx = 0.f; my = 0.f; }  // empty segment -> 0 (isfinite mask)
    *reinterpret_cast<float2*>(agg_sum + (size_t)n * DIM + lane * 2) = make_float2(sx, sy);
    *reinterpret_cast<float2*>(agg_max + (size_t)n * DIM + lane * 2) = make_float2(mx, my);
    if (lane == 0) deg[n] = (float)dg;

    // fused stats (branches 0..4), this node's columns 2*lane, 2*lane+1
    const float2 hv  = *reinterpret_cast<const float2*>(h + (size_t)n * DIM + lane * 2);
    const float2 hiv = *reinterpret_cast<const float2*>(h_in + (size_t)n * DIM + lane * 2);
    const float inv = 1.0f / fmaxf((float)dg, 1.0f);
    const float mnx = sx * inv, mny = sy * inv;
    s0x += hv.x;  q0x += hv.x * hv.x;   s0y += hv.y;  q0y += hv.y * hv.y;
    s1x += hiv.x; q1x += hiv.x * hiv.x; s1y += hiv.y; q1y += hiv.y * hiv.y;
    s2x += sx;    q2x += sx * sx;       s2y += sy;    q2y += sy * sy;
    s3x += mnx;   q3x += mnx * mnx;     s3y += mny;   q3y += mny * mny;
    s4x += mx;    q4x += mx * mx;       s4y += my;    q4y += my * my;
  }

  const int cA = 2 * lane, cB = 2 * lane + 1;
  atomicAdd(&lsum[0 * DIM + cA], s0x); atomicAdd(&lssq[0 * DIM + cA], q0x);
  atomicAdd(&lsum[0 * DIM + cB], s0y); atomicAdd(&lssq[0 * DIM + cB], q0y);
  atomicAdd(&lsum[1 * DIM + cA], s1x); atomicAdd(&lssq[1 * DIM + cA], q1x);
  atomicAdd(&lsum[1 * DIM + cB], s1y); atomicAdd(&lssq[1 * DIM + cB], q1y);
  atomicAdd(&lsum[2 * DIM + cA], s2x); atomicAdd(&lssq[2 * DIM + cA], q2x);
  atomicAdd(&lsum[2 * DIM + cB], s2y); atomicAdd(&lssq[2 * DIM + cB], q2y);
  atomicAdd(&lsum[3 * DIM + cA], s3x); atomicAdd(&lssq[3 * DIM + cA], q3x);
  atomicAdd(&lsum[3 * DIM + cB], s3y); atomicAdd(&lssq[3 * DIM + cB], q3y);
  atomicAdd(&lsum[4 * DIM + cA], s4x); atomicAdd(&lssq[4 * DIM + cA], q4x);
  atomicAdd(&lsum[4 * DIM + cB], s4y); atomicAdd(&lssq[4 * DIM + cB], q4y);
  __syncthreads();

  float* p = partials + (size_t)blockIdx.x * PART_W;
  for (int i = threadIdx.x; i < N_OPS * DIM; i += blockDim.x) {
    p[i] = lsum[i];
    p[N_OPS * DIM + i] = lssq[i];
  }
}

// ---- K5: fold 2048 partial rows -> ssum/sssq (64 blocks x 32 rows, coalesced) ----
__global__ void reduce_stats(const float* __restrict__ partials,
                             float* __restrict__ ssum_ssq) {
  const int b0 = blockIdx.x * (GATHER_NB / RED_NB);   // 32 rows per block
  float acc[PART_W / 256];                            // 5 per thread
#pragma unroll
  for (int j = 0; j < PART_W / 256; ++j) acc[j] = 0.f;
#pragma unroll 4
  for (int k = 0; k < GATHER_NB / RED_NB; ++k) {
    const float* p = partials + (size_t)(b0 + k) * PART_W;
#pragma unroll
    for (int j = 0; j < PART_W / 256; ++j)
      acc[j] += p[j * 256 + threadIdx.x];
  }
#pragma unroll
  for (int j = 0; j < PART_W / 256; ++j)
    unsafeAtomicAdd(&ssum_ssq[j * 256 + threadIdx.x], acc[j]);
}

// ---- K6: fused BN + ReLU + weighted sum (derives mu/rsig in-block) ----
__global__ void out_kernel(const float* __restrict__ h,
                           const float* __restrict__ h_in,
                           const float* __restrict__ agg_sum,
                           const float* __restrict__ agg_max,
                           const float* __restrict__ deg,
                           const float* __restrict__ ssum_ssq,
                           const float* __restrict__ gamma,
                           const float* __restrict__ beta,
                           const float* __restrict__ w,
                           float* __restrict__ out) {
  __shared__ float smu[N_OPS * DIM], srs[N_OPS * DIM], sg[N_OPS * DIM], sb[N_OPS * DIM];
  __shared__ float sw[N_OPS];
  const float invn = 1.0f / (float)N_NODES;
  for (int i = threadIdx.x; i < N_OPS * DIM; i += blockDim.x) {
    const float m = ssum_ssq[i] * invn;
    float v = ssum_ssq[N_OPS * DIM + i] * invn - m * m;
    v = fmaxf(v, 0.0f);
    smu[i] = m;
    srs[i] = rsqrtf(v + EPS);
    sg[i] = gamma[i]; sb[i] = beta[i];
  }
  if (threadIdx.x < N_OPS) sw[threadIdx.x] = w[threadIdx.x];
  __syncthreads();

  const int ngroups = N_NODES * (DIM / 4);
  for (int g = blockIdx.x * blockDim.x + threadIdx.x; g < ngroups;
       g += gridDim.x * blockDim.x) {
    const int n  = g >> 5;
    const int d4 = (g & 31) * 4;
    const size_t off = (size_t)n * DIM + d4;

    const float4 v0 = *reinterpret_cast<const float4*>(h + off);
    const float4 v1 = *reinterpret_cast<const float4*>(h_in + off);
    const float4 v2 = *reinterpret_cast<const float4*>(agg_sum + off);
    const float4 v4 = *reinterpret_cast<const float4*>(agg_max + off);
    const float dg  = deg[n];
    const float inv = 1.0f / fmaxf(dg, 1.0f);

    float vals[N_OPS][4];
    vals[0][0] = v0.x; vals[0][1] = v0.y; vals[0][2] = v0.z; vals[0][3] = v0.w;
    vals[1][0] = v1.x; vals[1][1] = v1.y; vals[1][2] = v1.z; vals[1][3] = v1.w;
    vals[2][0] = v2.x; vals[2][1] = v2.y; vals[2][2] = v2.z; vals[2][3] = v2.w;
    vals[3][0] = v2.x * inv; vals[3][1] = v2.y * inv;
    vals[3][2] = v2.z * inv; vals[3][3] = v2.w * inv;
    vals[4][0] = v4.x; vals[4][1] = v4.y; vals[4][2] = v4.z; vals[4][3] = v4.w;

    float acc[4] = {0.0f, 0.0f, 0.0f, 0.0f};
#pragma unroll
    for (int b = 0; b < N_OPS; ++b) {
      const float wb = sw[b];
#pragma unroll
      for (int c = 0; c < 4; ++c) {
        const int dd = b * DIM + d4 + c;
        const float xh = (vals[b][c] - smu[dd]) * srs[dd];
        const float y  = fmaf(sg[dd], xh, sb[dd]);
        acc[c] = fmaf(wb, fmaxf(y, 0.0f), acc[c]);
      }
    }
    *reinterpret_cast<float4*>(out + off) = make_float4(acc[0], acc[1], acc[2], acc[3]);
  }
}

extern "C" void kernel_launch(void* const* d_in, const int* in_sizes, int n_in,
                              void* d_out, int out_size, void* d_ws, size_t ws_size,
                              hipStream_t stream) {
  const float* w     = (const float*)d_in[0];
  const int*   ei    = (const int*)d_in[1];
  const float* h     = (const float*)d_in[2];
  const float* h_in  = (const float*)d_in[3];
  const float* gamma = (const float*)d_in[4];
  const float* beta  = (const float*)d_in[5];
  float* out = (float*)d_out;

  const size_t ND = (size_t)N_NODES * DIM;
  float* ws       = (float*)d_ws;
  float* agg_sum  = ws;                               // ND floats
  int*   cnt      = (int*)(ws + ND);                  // N ints      <- zeroed
  float* ssum_ssq = (float*)(cnt + N_NODES);          // 1280 floats <- zeroed
  int*   offs     = (int*)(ssum_ssq + PART_W);        // N+1 ints
  int*   cursor   = offs + N_NODES + 1;               // N ints
  float* deg      = (float*)(cursor + N_NODES);       // N floats
  int*   csr_src  = (int*)(deg + N_NODES);            // E ints
  int*   bsum     = csr_src + N_EDGES;                // 10 ints (pad to 12)
  float* partials = (float*)(bsum + 12);              // 2048*1280 floats
  float* agg_max  = out;                              // ND floats (overwritten last)

  hipMemsetAsync(cnt, 0, (N_NODES + PART_W) * sizeof(int), stream);

  hist_kernel<<<(N_EDGES / 4 + 255) / 256, 256, 0, stream>>>(ei, cnt);
  scanA_kernel<<<SCAN_NB, 1024, 0, stream>>>(cnt, bsum);
  scanC_kernel<<<SCAN_NB, 1024, 0, stream>>>(cnt, bsum, offs, cursor);
  csr_fill_kernel<<<(N_EDGES / 4 + 255) / 256, 256, 0, stream>>>(ei, cursor, csr_src);
  gather_stats_kernel<<<GATHER_NB, 256, 0, stream>>>(csr_src, offs, h, h_in,
                                                     agg_sum, agg_max, deg, partials);
  reduce_stats<<<RED_NB, 256, 0, stream>>>(partials, ssum_ssq);
  out_kernel<<<2048, 256, 0, stream>>>(h, h_in, agg_sum, agg_max, deg, ssum_ssq,
                                       gamma, beta, w, out);
}

// Round 8
// 180.589 us; speedup vs baseline: 3.5400x; 1.0598x over previous
//
#include <hip/hip_runtime.h>
#include <hip/hip_bf16.h>

#define N_NODES 40000
#define N_EDGES 640000
#define DIM 128
#define N_OPS 5
#define EPS 1e-5f
#define SCAN_CHUNK 4096
#define SCAN_NB ((N_NODES + SCAN_CHUNK - 1) / SCAN_CHUNK)   // 10
#define GATHER_NB 2048
#define STAT_NB 512                   // blocks per stats kernel
#define PART_W (2 * N_OPS * DIM)      // 1280: [sum0..sum4 | ssq0..ssq4]
#define PART_ROWS (2 * STAT_NB)       // 1024 partial rows total
#define RED_NB 64

// ---- K1: histogram of dst + branch-0/1 column stats (independent of graph) ----
__global__ void __launch_bounds__(256)
hist_stats01_kernel(const int* __restrict__ ei, int* __restrict__ cnt,
                    const float* __restrict__ h, const float* __restrict__ h_in,
                    float* __restrict__ partials) {
  __shared__ float lred[PART_W];
  for (int i = threadIdx.x; i < PART_W; i += 256) lred[i] = 0.f;
  __syncthreads();

  const int gtid = blockIdx.x * 256 + threadIdx.x;
  const int gsz  = gridDim.x * 256;          // 512*256 = 131072 (mult of 32)

  // A: histogram (int4, 4 edges/thread)
  for (int t = gtid; t < N_EDGES / 4; t += gsz) {
    const int4 d = reinterpret_cast<const int4*>(ei + N_EDGES)[t];
    atomicAdd(&cnt[d.x], 1);
    atomicAdd(&cnt[d.y], 1);
    atomicAdd(&cnt[d.z], 1);
    atomicAdd(&cnt[d.w], 1);
  }

  // B: column sums/sumsq of h (branch 0) and h_in (branch 1), float4
  float s0[4] = {0, 0, 0, 0}, q0[4] = {0, 0, 0, 0};
  float s1[4] = {0, 0, 0, 0}, q1[4] = {0, 0, 0, 0};
  const int NG = N_NODES * (DIM / 4);
  for (int g = gtid; g < NG; g += gsz) {
    const float4 a = reinterpret_cast<const float4*>(h)[g];
    const float4 b = reinterpret_cast<const float4*>(h_in)[g];
    s0[0] += a.x; q0[0] += a.x * a.x;  s0[1] += a.y; q0[1] += a.y * a.y;
    s0[2] += a.z; q0[2] += a.z * a.z;  s0[3] += a.w; q0[3] += a.w * a.w;
    s1[0] += b.x; q1[0] += b.x * b.x;  s1[1] += b.y; q1[1] += b.y * b.y;
    s1[2] += b.z; q1[2] += b.z * b.z;  s1[3] += b.w; q1[3] += b.w * b.w;
  }
  const int c4 = (threadIdx.x & 31) * 4;     // gsz mult of 32 -> column fixed
#pragma unroll
  for (int j = 0; j < 4; ++j) {
    atomicAdd(&lred[0 * DIM + c4 + j], s0[j]);
    atomicAdd(&lred[1 * DIM + c4 + j], s1[j]);
    atomicAdd(&lred[N_OPS * DIM + 0 * DIM + c4 + j], q0[j]);
    atomicAdd(&lred[N_OPS * DIM + 1 * DIM + c4 + j], q1[j]);
  }
  __syncthreads();
  float* p = partials + (size_t)blockIdx.x * PART_W;   // rows [0, STAT_NB)
  for (int i = threadIdx.x; i < PART_W; i += 256) p[i] = lred[i];
}

// ---- K2a: per-chunk totals (10 blocks x 1024) ----
__global__ void scanA_kernel(const int* __restrict__ cnt, int* __restrict__ bsum) {
  __shared__ int ws[16];
  const int tid = threadIdx.x, b = blockIdx.x;
  const int i0 = b * SCAN_CHUNK + tid * 4;
  int s = 0;
  if (i0 + 3 < N_NODES) {
    const int4 x = *reinterpret_cast<const int4*>(cnt + i0);
    s = x.x + x.y + x.z + x.w;
  } else {
#pragma unroll
    for (int k = 0; k < 4; ++k) if (i0 + k < N_NODES) s += cnt[i0 + k];
  }
#pragma unroll
  for (int off = 32; off; off >>= 1) s += __shfl_down(s, off, 64);
  if ((tid & 63) == 0) ws[tid >> 6] = s;
  __syncthreads();
  if (tid == 0) {
    int t = 0;
#pragma unroll
    for (int k = 0; k < 16; ++k) t += ws[k];
    bsum[b] = t;
  }
}

// ---- K2b: local exclusive scan per chunk; chunk base derived inline ----
__global__ void scanC_kernel(const int* __restrict__ cnt, const int* __restrict__ bsum,
                             int* __restrict__ offs, int* __restrict__ cursor) {
  __shared__ int wsum[16];
  __shared__ int sbase;
  const int tid  = threadIdx.x;       // 1024
  const int lane = tid & 63;
  const int wid  = tid >> 6;
  const int b    = blockIdx.x;
  if (tid == 0) {
    int acc = 0;
    for (int k = 0; k < b; ++k) acc += bsum[k];
    sbase = acc;
  }
  const int i0 = b * SCAN_CHUNK + tid * 4;
  int x0 = 0, x1 = 0, x2 = 0, x3 = 0;
  if (i0 + 3 < N_NODES) {
    const int4 x4 = *reinterpret_cast<const int4*>(cnt + i0);
    x0 = x4.x; x1 = x4.y; x2 = x4.z; x3 = x4.w;
  } else if (i0 < N_NODES) {
    x0 = cnt[i0];
    if (i0 + 1 < N_NODES) x1 = cnt[i0 + 1];
    if (i0 + 2 < N_NODES) x2 = cnt[i0 + 2];
  }
  const int my4 = x0 + x1 + x2 + x3;
  int v = my4;
#pragma unroll
  for (int off = 1; off < 64; off <<= 1) {
    int t = __shfl_up(v, off, 64);
    if (lane >= off) v += t;
  }
  if (lane == 63) wsum[wid] = v;
  __syncthreads();
  if (wid == 0 && lane < 16) {
    int wv = wsum[lane];
#pragma unroll
    for (int off = 1; off < 16; off <<= 1) {
      int t = __shfl_up(wv, off, 64);
      if (lane >= off) wv += t;
    }
    wsum[lane] = wv;
  }
  __syncthreads();
  const int wave_excl = (wid == 0) ? 0 : wsum[wid - 1];
  int excl = v - my4 + wave_excl + sbase;
  if (i0 < N_NODES) {
    offs[i0] = excl; cursor[i0] = excl; excl += x0;
    if (i0 + 1 < N_NODES) { offs[i0 + 1] = excl; cursor[i0 + 1] = excl; excl += x1; }
    if (i0 + 2 < N_NODES) { offs[i0 + 2] = excl; cursor[i0 + 2] = excl; excl += x2; }
    if (i0 + 3 < N_NODES) { offs[i0 + 3] = excl; cursor[i0 + 3] = excl; }
  }
  if (b == 0 && tid == 0) offs[N_NODES] = N_EDGES;
}

// ---- K3: fill CSR (4 edges/thread, int4) ----
__global__ void csr_fill_kernel(const int* __restrict__ ei, int* __restrict__ cursor,
                                int* __restrict__ csr_src) {
  const int t = blockIdx.x * blockDim.x + threadIdx.x;
  if (t < N_EDGES / 4) {
    const int4 s = reinterpret_cast<const int4*>(ei)[t];
    const int4 d = reinterpret_cast<const int4*>(ei + N_EDGES)[t];
    csr_src[atomicAdd(&cursor[d.x], 1)] = s.x;
    csr_src[atomicAdd(&cursor[d.y], 1)] = s.y;
    csr_src[atomicAdd(&cursor[d.z], 1)] = s.z;
    csr_src[atomicAdd(&cursor[d.w], 1)] = s.w;
  }
}

// ---- K4: wave-per-node gather segment-reduce (sum + max) — PURE, unroll 8 ----
__global__ void __launch_bounds__(256)
gather_kernel(const int* __restrict__ csr_src,
              const int* __restrict__ offs,
              const float* __restrict__ h,
              float* __restrict__ agg_sum,
              float* __restrict__ agg_max,
              float* __restrict__ deg) {
  const int lane  = threadIdx.x & 63;
  const int wave  = (int)((blockIdx.x * blockDim.x + threadIdx.x) >> 6);
  const int nwave = (int)((gridDim.x * blockDim.x) >> 6);
  for (int n = wave; n < N_NODES; n += nwave) {
    const int beg = offs[n], end = offs[n + 1];
    float sx = 0.f, sy = 0.f;
    float mx = -INFINITY, my = -INFINITY;
    int e = beg;
    for (; e + 7 < end; e += 8) {
      float2 r[8];
#pragma unroll
      for (int k = 0; k < 8; ++k) {
        const int s = csr_src[e + k];
        r[k] = *reinterpret_cast<const float2*>(h + (size_t)s * DIM + lane * 2);
      }
#pragma unroll
      for (int k = 0; k < 8; ++k) {
        sx += r[k].x; sy += r[k].y;
        mx = fmaxf(mx, r[k].x); my = fmaxf(my, r[k].y);
      }
    }
    for (; e + 3 < end; e += 4) {
      float2 r[4];
#pragma unroll
      for (int k = 0; k < 4; ++k) {
        const int s = csr_src[e + k];
        r[k] = *reinterpret_cast<const float2*>(h + (size_t)s * DIM + lane * 2);
      }
#pragma unroll
      for (int k = 0; k < 4; ++k) {
        sx += r[k].x; sy += r[k].y;
        mx = fmaxf(mx, r[k].x); my = fmaxf(my, r[k].y);
      }
    }
    for (; e < end; ++e) {
      const int s = csr_src[e];
      const float2 a = *reinterpret_cast<const float2*>(h + (size_t)s * DIM + lane * 2);
      sx += a.x; sy += a.y;
      mx = fmaxf(mx, a.x); my = fmaxf(my, a.y);
    }
    const int dg = end - beg;
    if (dg == 0) { mx = 0.f; my = 0.f; }  // empty segment -> 0 (isfinite mask)
    *reinterpret_cast<float2*>(agg_sum + (size_t)n * DIM + lane * 2) = make_float2(sx, sy);
    *reinterpret_cast<float2*>(agg_max + (size_t)n * DIM + lane * 2) = make_float2(mx, my);
    if (lane == 0) deg[n] = (float)dg;
  }
}

// ---- K5: branch-2/3/4 column stats from agg_sum/agg_max (L2/L3-hot) ----
__global__ void __launch_bounds__(256)
stats234_kernel(const float* __restrict__ agg_sum,
                const float* __restrict__ agg_max,
                const float* __restrict__ deg,
                float* __restrict__ partials) {
  __shared__ float lred[PART_W];
  for (int i = threadIdx.x; i < PART_W; i += 256) lred[i] = 0.f;
  __syncthreads();

  const int gtid = blockIdx.x * 256 + threadIdx.x;
  const int gsz  = gridDim.x * 256;           // 512*256 (mult of 32)
  float s2[4] = {0, 0, 0, 0}, q2[4] = {0, 0, 0, 0};
  float s3[4] = {0, 0, 0, 0}, q3[4] = {0, 0, 0, 0};
  float s4[4] = {0, 0, 0, 0}, q4[4] = {0, 0, 0, 0};
  const int NG = N_NODES * (DIM / 4);
  for (int g = gtid; g < NG; g += gsz) {
    const int n = g >> 5;
    const float4 v2 = reinterpret_cast<const float4*>(agg_sum)[g];
    const float4 v4 = reinterpret_cast<const float4*>(agg_max)[g];
    const float inv = 1.0f / fmaxf(deg[n], 1.0f);
    const float m0 = v2.x * inv, m1 = v2.y * inv, m2 = v2.z * inv, m3 = v2.w * inv;
    s2[0] += v2.x; q2[0] += v2.x * v2.x;  s2[1] += v2.y; q2[1] += v2.y * v2.y;
    s2[2] += v2.z; q2[2] += v2.z * v2.z;  s2[3] += v2.w; q2[3] += v2.w * v2.w;
    s3[0] += m0;   q3[0] += m0 * m0;      s3[1] += m1;   q3[1] += m1 * m1;
    s3[2] += m2;   q3[2] += m2 * m2;      s3[3] += m3;   q3[3] += m3 * m3;
    s4[0] += v4.x; q4[0] += v4.x * v4.x;  s4[1] += v4.y; q4[1] += v4.y * v4.y;
    s4[2] += v4.z; q4[2] += v4.z * v4.z;  s4[3] += v4.w; q4[3] += v4.w * v4.w;
  }
  const int c4 = (threadIdx.x & 31) * 4;
#pragma unroll
  for (int j = 0; j < 4; ++j) {
    atomicAdd(&lred[2 * DIM + c4 + j], s2[j]);
    atomicAdd(&lred[3 * DIM + c4 + j], s3[j]);
    atomicAdd(&lred[4 * DIM + c4 + j], s4[j]);
    atomicAdd(&lred[N_OPS * DIM + 2 * DIM + c4 + j], q2[j]);
    atomicAdd(&lred[N_OPS * DIM + 3 * DIM + c4 + j], q3[j]);
    atomicAdd(&lred[N_OPS * DIM + 4 * DIM + c4 + j], q4[j]);
  }
  __syncthreads();
  float* p = partials + (size_t)(STAT_NB + blockIdx.x) * PART_W;  // rows [STAT_NB, 2*STAT_NB)
  for (int i = threadIdx.x; i < PART_W; i += 256) p[i] = lred[i];
}

// ---- K6: fold 1024 partial rows -> ssum_ssq (64 blocks x 16 rows, coalesced) ----
__global__ void reduce_stats(const float* __restrict__ partials,
                             float* __restrict__ ssum_ssq) {
  const int b0 = blockIdx.x * (PART_ROWS / RED_NB);   // 16 rows per block
  float acc[PART_W / 256];                            // 5 per thread
#pragma unroll
  for (int j = 0; j < PART_W / 256; ++j) acc[j] = 0.f;
#pragma unroll 4
  for (int k = 0; k < PART_ROWS / RED_NB; ++k) {
    const float* p = partials + (size_t)(b0 + k) * PART_W;
#pragma unroll
    for (int j = 0; j < PART_W / 256; ++j)
      acc[j] += p[j * 256 + threadIdx.x];
  }
#pragma unroll
  for (int j = 0; j < PART_W / 256; ++j)
    unsafeAtomicAdd(&ssum_ssq[j * 256 + threadIdx.x], acc[j]);
}

// ---- K7: fused BN + ReLU + weighted sum (derives mu/rsig in-block) ----
__global__ void out_kernel(const float* __restrict__ h,
                           const float* __restrict__ h_in,
                           const float* __restrict__ agg_sum,
                           const float* __restrict__ agg_max,
                           const float* __restrict__ deg,
                           const float* __restrict__ ssum_ssq,
                           const float* __restrict__ gamma,
                           const float* __restrict__ beta,
                           const float* __restrict__ w,
                           float* __restrict__ out) {
  __shared__ float smu[N_OPS * DIM], srs[N_OPS * DIM], sg[N_OPS * DIM], sb[N_OPS * DIM];
  __shared__ float sw[N_OPS];
  const float invn = 1.0f / (float)N_NODES;
  for (int i = threadIdx.x; i < N_OPS * DIM; i += blockDim.x) {
    const float m = ssum_ssq[i] * invn;
    float v = ssum_ssq[N_OPS * DIM + i] * invn - m * m;
    v = fmaxf(v, 0.0f);
    smu[i] = m;
    srs[i] = rsqrtf(v + EPS);
    sg[i] = gamma[i]; sb[i] = beta[i];
  }
  if (threadIdx.x < N_OPS) sw[threadIdx.x] = w[threadIdx.x];
  __syncthreads();

  const int ngroups = N_NODES * (DIM / 4);
  for (int g = blockIdx.x * blockDim.x + threadIdx.x; g < ngroups;
       g += gridDim.x * blockDim.x) {
    const int n  = g >> 5;
    const int d4 = (g & 31) * 4;
    const size_t off = (size_t)n * DIM + d4;

    const float4 v0 = *reinterpret_cast<const float4*>(h + off);
    const float4 v1 = *reinterpret_cast<const float4*>(h_in + off);
    const float4 v2 = *reinterpret_cast<const float4*>(agg_sum + off);
    const float4 v4 = *reinterpret_cast<const float4*>(agg_max + off);
    const float dg  = deg[n];
    const float inv = 1.0f / fmaxf(dg, 1.0f);

    float vals[N_OPS][4];
    vals[0][0] = v0.x; vals[0][1] = v0.y; vals[0][2] = v0.z; vals[0][3] = v0.w;
    vals[1][0] = v1.x; vals[1][1] = v1.y; vals[1][2] = v1.z; vals[1][3] = v1.w;
    vals[2][0] = v2.x; vals[2][1] = v2.y; vals[2][2] = v2.z; vals[2][3] = v2.w;
    vals[3][0] = v2.x * inv; vals[3][1] = v2.y * inv;
    vals[3][2] = v2.z * inv; vals[3][3] = v2.w * inv;
    vals[4][0] = v4.x; vals[4][1] = v4.y; vals[4][2] = v4.z; vals[4][3] = v4.w;

    float acc[4] = {0.0f, 0.0f, 0.0f, 0.0f};
#pragma unroll
    for (int b = 0; b < N_OPS; ++b) {
      const float wb = sw[b];
#pragma unroll
      for (int c = 0; c < 4; ++c) {
        const int dd = b * DIM + d4 + c;
        const float xh = (vals[b][c] - smu[dd]) * srs[dd];
        const float y  = fmaf(sg[dd], xh, sb[dd]);
        acc[c] = fmaf(wb, fmaxf(y, 0.0f), acc[c]);
      }
    }
    *reinterpret_cast<float4*>(out + off) = make_float4(acc[0], acc[1], acc[2], acc[3]);
  }
}

extern "C" void kernel_launch(void* const* d_in, const int* in_sizes, int n_in,
                              void* d_out, int out_size, void* d_ws, size_t ws_size,
                              hipStream_t stream) {
  const float* w     = (const float*)d_in[0];
  const int*   ei    = (const int*)d_in[1];
  const float* h     = (const float*)d_in[2];
  const float* h_in  = (const float*)d_in[3];
  const float* gamma = (const float*)d_in[4];
  const float* beta  = (const float*)d_in[5];
  float* out = (float*)d_out;

  const size_t ND = (size_t)N_NODES * DIM;
  float* ws       = (float*)d_ws;
  float* agg_sum  = ws;                               // ND floats
  int*   cnt      = (int*)(ws + ND);                  // N ints      <- zeroed
  float* ssum_ssq = (float*)(cnt + N_NODES);          // 1280 floats <- zeroed
  int*   offs     = (int*)(ssum_ssq + PART_W);        // N+1 ints
  int*   cursor   = offs + N_NODES + 1;               // N ints
  float* deg      = (float*)(cursor + N_NODES);       // N floats
  int*   csr_src  = (int*)(deg + N_NODES);            // E ints
  int*   bsum     = csr_src + N_EDGES;                // 10 ints (pad to 12)
  float* partials = (float*)(bsum + 12);              // 1024*1280 floats
  float* agg_max  = out;                              // ND floats (overwritten last)

  hipMemsetAsync(cnt, 0, (N_NODES + PART_W) * sizeof(int), stream);

  hist_stats01_kernel<<<STAT_NB, 256, 0, stream>>>(ei, cnt, h, h_in, partials);
  scanA_kernel<<<SCAN_NB, 1024, 0, stream>>>(cnt, bsum);
  scanC_kernel<<<SCAN_NB, 1024, 0, stream>>>(cnt, bsum, offs, cursor);
  csr_fill_kernel<<<(N_EDGES / 4 + 255) / 256, 256, 0, stream>>>(ei, cursor, csr_src);
  gather_kernel<<<GATHER_NB, 256, 0, stream>>>(csr_src, offs, h, agg_sum, agg_max, deg);
  stats234_kernel<<<STAT_NB, 256, 0, stream>>>(agg_sum, agg_max, deg, partials);
  reduce_stats<<<RED_NB, 256, 0, stream>>>(partials, ssum_ssq);
  out_kernel<<<2048, 256, 0, stream>>>(h, h_in, agg_sum, agg_max, deg, ssum_ssq,
                                       gamma, beta, w, out);
}